// Round 5
// baseline (467.897 us; speedup 1.0000x reference)
//
#include <hip/hip_runtime.h>
#include <hip/hip_fp16.h>
#include <math.h>

// WaveNet collapsed to the last time column (symmetric pad (K-1)*d puts the
// k=1 tap of every dilated conv in the zero pad at the final position), fused
// into ONE kernel with device-scope flag pipelining:
//   blocks 0-7    : per-batch serial 40-layer recurrence (wave0) + publisher
//                   wave (wave1) that zeroes accumulators and streams z.
//   blocks 8-47   : per-layer fp32->fp16 weight repack (k=0 taps), flag wf[l].
//   blocks 48-367 : per-(layer,batch) skip matvec; preload weights in regs,
//                   spin on zf, atomicAdd into hsum, flag sf.
//   blocks 368-399: per-(batch,quarter) end1+end2; preload 64 rows of end1_w,
//                   spin on all sf of the batch, write out[b].
// Flags use a MAGIC value so the 0xAA ws poison never reads as "set".

#define NL 40
#define TLEN 8192
#define MAGIC 0x13572468

// ws float-offset layout
//   [0 .. 61439]   fp16 weight blobs: [40 layers][64 lanes][48 halfs]
#define F_Z    61440            // [40][8][32] z values
#define F_H    71680            // [8][256] skip accumulator
#define F_OB   73728            // [8] end2 partial accumulator
#define F_FLAG 73744            // int flags: wf[40], zf[320], sf[320], ef[32]

__device__ __forceinline__ void wait_magic(const int* p) {
    while (__hip_atomic_load(p, __ATOMIC_ACQUIRE, __HIP_MEMORY_SCOPE_AGENT)
           != MAGIC)
        __builtin_amdgcn_s_sleep(1);
}
__device__ __forceinline__ void set_magic(int* p) {
    __hip_atomic_store(p, MAGIC, __ATOMIC_RELEASE, __HIP_MEMORY_SCOPE_AGENT);
}
__device__ __forceinline__ float ldf(const float* p) {
    return __hip_atomic_load(p, __ATOMIC_RELAXED, __HIP_MEMORY_SCOPE_AGENT);
}

struct WBlob { float4 q[6]; };   // 48 halfs: 16 filter, 16 gate, 16 res taps

__device__ __forceinline__ float dot16h(const float4& a, const float4& b,
                                        const float* c) {
    const __half2* h0 = (const __half2*)&a;
    const __half2* h1 = (const __half2*)&b;
    float acc = 0.f;
#pragma unroll
    for (int i = 0; i < 4; ++i) {
        float2 w = __half22float2(h0[i]);
        acc += w.x * c[2*i] + w.y * c[2*i+1];
    }
#pragma unroll
    for (int i = 0; i < 4; ++i) {
        float2 w = __half22float2(h1[i]);
        acc += w.x * c[8+2*i] + w.y * c[8+2*i+1];
    }
    return acc;
}

__device__ __forceinline__ float tanh_fast(float f) {
    f = fminf(fmaxf(f, -15.f), 15.f);
    float e2 = __expf(2.f * f);
    return (e2 - 1.f) / (e2 + 1.f);
}

__global__ __launch_bounds__(256) void wavenet_fused(
    const float* __restrict__ x, const float* __restrict__ start_w,
    const float* __restrict__ filter_w, const float* __restrict__ gate_w,
    const float* __restrict__ res_w, const float* __restrict__ skip_w,
    const float* __restrict__ end1_w, const float* __restrict__ end1_b,
    const float* __restrict__ end2_w, const float* __restrict__ end2_b,
    float* __restrict__ ws, float* __restrict__ out)
{
    __shared__ __align__(16) float zring[NL * 32];
    __shared__ __align__(16) float csm[32];
    __shared__ __align__(16) float smem[256];   // zsm (skip) / hsm (end1)
    __shared__ float psum[64][5];
    __shared__ int prog;

    int* flags = (int*)(ws + F_FLAG);
    int* wf = flags;          // [40]  layer weights repacked
    int* zf = flags + 40;     // [320] z[l,b] published
    int* sf = flags + 360;    // [320] skip[l,b] accumulated
    int* ef = flags + 680;    // [32]  end1 quarter done
    float* zbuf = ws + F_Z;
    float* hsum = ws + F_H;
    float* obuf = ws + F_OB;

    const int id = blockIdx.x;
    const int t  = threadIdx.x;

    if (id < 8) {
        // ------------------- recurrence block, batch b -------------------
        const int b = id;
        if (t == 0) prog = 0;
        __syncthreads();
        const int wave = t >> 6;
        if (wave >= 2) return;
        const int lane = t & 63;

        if (wave == 1) {
            // publisher: zero accumulators, then stream z per layer
            hsum[b*256 + lane]       = 0.f;
            hsum[b*256 + lane + 64]  = 0.f;
            hsum[b*256 + lane + 128] = 0.f;
            hsum[b*256 + lane + 192] = 0.f;
            if (lane == 0) obuf[b] = 0.f;
            for (int l = 0; l < NL; ++l) {
                while (__hip_atomic_load(&prog, __ATOMIC_ACQUIRE,
                                         __HIP_MEMORY_SCOPE_WORKGROUP) <= l)
                    ;
                if (lane < 32)
                    zbuf[(l*8 + b)*32 + lane] = zring[l*32 + lane];
                if (lane == 0) set_magic(&zf[l*8 + b]);
            }
            return;
        }

        // wave 0: the serial chain. lane = (h<<5)|ch, dot split in 2 halves.
        const int ch = lane & 31, h = lane >> 5;
        if (h == 0) {
            float acc = 0.f;
#pragma unroll
            for (int j = 0; j < 6; ++j)
                acc += start_w[ch*6 + j] * x[(b*6 + j)*TLEN + TLEN - 1];
            csm[ch] = acc;
        }
        __builtin_amdgcn_wave_barrier();

        const __half* fgh = (const __half*)ws;
        const size_t laneoff = (size_t)(ch*2 + h) * 48;
        WBlob w[3];
        wait_magic(&wf[0]);
        { const float4* p = (const float4*)(fgh + laneoff);
#pragma unroll
          for (int i = 0; i < 6; ++i) w[0].q[i] = p[i]; }
        wait_magic(&wf[1]);
        { const float4* p = (const float4*)(fgh + 3072 + laneoff);
#pragma unroll
          for (int i = 0; i < 6; ++i) w[1].q[i] = p[i]; }

        for (int l = 0; l < NL; ++l) {
            if (l + 2 < NL) {                       // 2-deep reg prefetch
                wait_magic(&wf[l+2]);
                const float4* p =
                    (const float4*)(fgh + (size_t)(l+2)*3072 + laneoff);
#pragma unroll
                for (int i = 0; i < 6; ++i) w[(l+2)%3].q[i] = p[i];
            }
            const WBlob& W = w[l%3];
            float cc[16];
            { const float4* cp = (const float4*)(csm + h*16);
#pragma unroll
              for (int i = 0; i < 4; ++i) ((float4*)cc)[i] = cp[i]; }
            float f = dot16h(W.q[0], W.q[1], cc);
            float g = dot16h(W.q[2], W.q[3], cc);
            f += __shfl_xor(f, 32, 64);
            g += __shfl_xor(g, 32, 64);
            float z = tanh_fast(f) * (1.f / (1.f + __expf(-g)));
            if (h == 0) zring[l*32 + ch] = z;
            __builtin_amdgcn_wave_barrier();
            if (lane == 0)                           // unblock publisher
                __hip_atomic_store(&prog, l + 1, __ATOMIC_RELEASE,
                                   __HIP_MEMORY_SCOPE_WORKGROUP);
            float zz[16];
            { const float4* zp = (const float4*)(zring + l*32 + h*16);
#pragma unroll
              for (int i = 0; i < 4; ++i) ((float4*)zz)[i] = zp[i]; }
            float r = dot16h(W.q[4], W.q[5], zz);
            r += __shfl_xor(r, 32, 64);
            float cnew = r + z;
            __builtin_amdgcn_wave_barrier();
            if (h == 0) csm[ch] = cnew;
            __builtin_amdgcn_wave_barrier();
        }
        return;
    }
    else if (id < 48) {
        // ------------------- repack block, layer l -----------------------
        const int l = id - 8;
        __half* dst = (__half*)ws + (size_t)l * 3072;
        for (int e = t; e < 3072; e += 256) {
            const int cc = e / 48, r = e - cc*48;
            const int ch = cc >> 1, h = cc & 1;
            float v;
            if (r < 16)      v = filter_w[((l*32+ch)*32 + h*16 + r)*2];
            else if (r < 32) v = gate_w [((l*32+ch)*32 + h*16 + (r-16))*2];
            else             v = res_w  [ (l*32+ch)*32 + h*16 + (r-32)];
            dst[e] = __float2half(v);
        }
        __threadfence();
        __syncthreads();
        if (t == 0) set_magic(&wf[l]);
    }
    else if (id < 368) {
        // ------------------- skip consumer (l, b) ------------------------
        const int s = id - 48, l = s >> 3, b = s & 7;
        float4 wreg[8];                       // preload BEFORE spinning
        const float4* wp = (const float4*)(skip_w + (size_t)(l*256 + t)*32);
#pragma unroll
        for (int i = 0; i < 8; ++i) wreg[i] = wp[i];
        if (t == 0) wait_magic(&zf[l*8 + b]);
        __syncthreads();
        if (t < 32) smem[t] = ldf(&zbuf[(l*8 + b)*32 + t]);
        __syncthreads();
        const float4* z4 = (const float4*)smem;
        float acc = 0.f;
#pragma unroll
        for (int i = 0; i < 8; ++i) {
            float4 wv = wreg[i], zv = z4[i];
            acc += wv.x*zv.x + wv.y*zv.y + wv.z*zv.z + wv.w*zv.w;
        }
        atomicAdd(&hsum[b*256 + t], acc);
        __threadfence();
        __syncthreads();
        if (t == 0) set_magic(&sf[l*8 + b]);
    }
    else {
        // ------------------- end1 + end2 (b, quarter q) ------------------
        const int s = id - 368, b = s >> 2, q = s & 3;
        const int p = t >> 6, oc = t & 63, row = q*64 + oc;
        float4 wreg[16];                      // preload BEFORE spinning
        const float4* wp = (const float4*)(end1_w + (size_t)row*256 + p*64);
#pragma unroll
        for (int i = 0; i < 16; ++i) wreg[i] = wp[i];
        if (t < NL) wait_magic(&sf[t*8 + b]);
        __syncthreads();
        smem[t] = fmaxf(ldf(&hsum[b*256 + t]), 0.f);   // relu(skip_sum)
        __syncthreads();
        const float4* h4 = (const float4*)(smem + p*64);
        float acc = 0.f;
#pragma unroll
        for (int i = 0; i < 16; ++i) {
            float4 wv = wreg[i], hv = h4[i];
            acc += wv.x*hv.x + wv.y*hv.y + wv.z*hv.z + wv.w*hv.w;
        }
        psum[oc][p] = acc;
        __syncthreads();
        if (t < 64) {
            const int rr = q*64 + t;
            float e = psum[t][0] + psum[t][1] + psum[t][2] + psum[t][3]
                    + end1_b[rr];
            e = fmaxf(e, 0.f);
            float pe = e * end2_w[rr];
#pragma unroll
            for (int off = 32; off > 0; off >>= 1)
                pe += __shfl_down(pe, off, 64);
            if (t == 0) {
                atomicAdd(&obuf[b], pe);
                set_magic(&ef[b*4 + q]);
                if (q == 0) {
                    wait_magic(&ef[b*4 + 0]);
                    wait_magic(&ef[b*4 + 1]);
                    wait_magic(&ef[b*4 + 2]);
                    wait_magic(&ef[b*4 + 3]);
                    out[b] = ldf(&obuf[b]) + end2_b[0];
                }
            }
        }
    }
}

extern "C" void kernel_launch(void* const* d_in, const int* in_sizes, int n_in,
                              void* d_out, int out_size, void* d_ws, size_t ws_size,
                              hipStream_t stream) {
    const float* x        = (const float*)d_in[0];
    const float* start_w  = (const float*)d_in[1];
    const float* filter_w = (const float*)d_in[2];
    const float* gate_w   = (const float*)d_in[3];
    const float* res_w    = (const float*)d_in[4];
    const float* skip_w   = (const float*)d_in[5];
    const float* end1_w   = (const float*)d_in[6];
    const float* end1_b   = (const float*)d_in[7];
    const float* end2_w   = (const float*)d_in[8];
    const float* end2_b   = (const float*)d_in[9];
    float* out = (float*)d_out;
    float* ws  = (float*)d_ws;

    wavenet_fused<<<dim3(400), dim3(256), 0, stream>>>(
        x, start_w, filter_w, gate_w, res_w, skip_w,
        end1_w, end1_b, end2_w, end2_b, ws, out);
}

// Round 6
// 107.474 us; speedup vs baseline: 4.3536x; 4.3536x over previous
//
#include <hip/hip_runtime.h>
#include <hip/hip_fp16.h>
#include <math.h>

// WaveNet collapsed to the last time column (symmetric pad (K-1)*d puts the
// k=1 tap of every dilated conv in the zero pad at the final position).
// Multi-kernel pipeline (device-scope spin sync measured 10x WORSE in R5 —
// kernel boundaries are cheaper than agent-scope flag spinning on MI355X):
//   K1  : repack filter/gate/res k=0 taps -> fp16 blob [40][6 quads][64][8],
//         start conv -> c0, zero hsum/obuf/counters.
//   K2  : ONE block, 8 waves (wave=batch), serial 40-layer recurrence,
//         4-deep static register ring prefetch; all waves share the blob
//         through one CU's L1 (8x reuse).
//   K3a : skip matvec (40x8 blocks), atomicAdd into hsum.
//   K3b : end1 matvec + fused end2 dot; last block per batch writes out[b].

#define NL 40
#define TLEN 8192

// ws float-offset layout
#define F_BLOB 0        // fp16 [40][6][64][8] = 122880 halfs = 61440 floats
#define F_C0   61440    // [8][32]
#define F_Z    61696    // [40][8][32]
#define F_H    71936    // [8][256]
#define F_OB   73984    // [8] float
#define F_CNT  73992    // [8] int

// ---------------------------------------------------------------- K1: prep
__device__ __forceinline__ float wsrc(const float* __restrict__ fw,
                                      const float* __restrict__ gw,
                                      const float* __restrict__ rw,
                                      int l, int ch, int h, int r) {
    const int base = (l * 32 + ch) * 32 + h * 16;
    if (r < 16) return fw[(base + r) * 2];          // filter k=0 tap
    if (r < 32) return gw[(base + (r - 16)) * 2];   // gate k=0 tap
    return rw[base + (r - 32)];                     // res
}

__global__ __launch_bounds__(256) void k1_prep(
    const float* __restrict__ x, const float* __restrict__ start_w,
    const float* __restrict__ filter_w, const float* __restrict__ gate_w,
    const float* __restrict__ res_w, float* __restrict__ ws)
{
    const int blk = blockIdx.x, t = threadIdx.x;
    if (blk < 240) {
        // one __half2 per thread; dest half idx e = l*3072 + i*512 + lane*8 + j
        const int p = blk * 256 + t;        // half2 index
        const int l = p / 1536;
        const int rem = p - l * 1536;
        const int i = rem >> 8;             // quad 0..5
        const int rem2 = rem & 255;
        const int lane = rem2 >> 2;         // hw lane 0..63
        const int jp = rem2 & 3;
        const int ch = lane & 31, h = lane >> 5;
        const int r0 = i * 8 + jp * 2;
        const float v0 = wsrc(filter_w, gate_w, res_w, l, ch, h, r0);
        const float v1 = wsrc(filter_w, gate_w, res_w, l, ch, h, r0 + 1);
        ((__half2*)ws)[p] = __floats2half2_rn(v0, v1);
    } else {
        // start conv + zero accumulators
        const int b = t >> 5, ch = t & 31;
        float acc = 0.f;
#pragma unroll
        for (int j = 0; j < 6; ++j)
            acc += start_w[ch * 6 + j] * x[(b * 6 + j) * TLEN + TLEN - 1];
        ws[F_C0 + t] = acc;
#pragma unroll
        for (int k = t; k < 2048; k += 256) ws[F_H + k] = 0.f;
        if (t < 8) { ws[F_OB + t] = 0.f; ((int*)(ws + F_CNT))[t] = 0; }
    }
}

// ------------------------------------------------------------ K2: recurrence
struct WBlob { float4 q[6]; };  // 48 halfs: filter[16], gate[16], res[16]

__device__ __forceinline__ float dot16h(const float4& a, const float4& b,
                                        const float* c) {
    const __half2* h0 = (const __half2*)&a;
    const __half2* h1 = (const __half2*)&b;
    float acc = 0.f;
#pragma unroll
    for (int i = 0; i < 4; ++i) {
        float2 w = __half22float2(h0[i]);
        acc += w.x * c[2*i] + w.y * c[2*i+1];
    }
#pragma unroll
    for (int i = 0; i < 4; ++i) {
        float2 w = __half22float2(h1[i]);
        acc += w.x * c[8+2*i] + w.y * c[8+2*i+1];
    }
    return acc;
}

__device__ __forceinline__ float tanh_fast(float f) {
    f = fminf(fmaxf(f, -15.f), 15.f);
    float e2 = __expf(2.f * f);
    return (e2 - 1.f) / (e2 + 1.f);
}

#define K2_PREFETCH(L4, D) do {                                              \
    if ((L4) < NL) {                                                         \
        _Pragma("unroll")                                                    \
        for (int i = 0; i < 6; ++i)                                          \
            w##D.q[i] = blob[(L4) * 384 + i * 64 + lane];                    \
    }                                                                        \
} while (0)

#define K2_STEP(L, D) do {                                                   \
    float cc[16];                                                            \
    { const float4* cp = (const float4*)(cs + h * 16);                       \
      _Pragma("unroll")                                                      \
      for (int i = 0; i < 4; ++i) ((float4*)cc)[i] = cp[i]; }                \
    float f = dot16h(w##D.q[0], w##D.q[1], cc);                              \
    float g = dot16h(w##D.q[2], w##D.q[3], cc);                              \
    f += __shfl_xor(f, 32, 64);                                              \
    g += __shfl_xor(g, 32, 64);                                              \
    float z = tanh_fast(f) * (1.f / (1.f + __expf(-g)));                     \
    if (h == 0) { zs[ch] = z; zbuf[((L) * 8 + b) * 32 + ch] = z; }           \
    __builtin_amdgcn_wave_barrier();                                         \
    float zz[16];                                                            \
    { const float4* zp = (const float4*)(zs + h * 16);                       \
      _Pragma("unroll")                                                      \
      for (int i = 0; i < 4; ++i) ((float4*)zz)[i] = zp[i]; }                \
    float r = dot16h(w##D.q[4], w##D.q[5], zz);                              \
    r += __shfl_xor(r, 32, 64);                                              \
    float cnew = r + z;                                                      \
    __builtin_amdgcn_wave_barrier();                                         \
    if (h == 0) cs[ch] = cnew;                                               \
    __builtin_amdgcn_wave_barrier();                                         \
    K2_PREFETCH((L) + 4, D);                                                 \
} while (0)

__global__ __launch_bounds__(512) void k2_recur(float* __restrict__ ws)
{
    const int t = threadIdx.x;
    const int b = t >> 6;               // wave = batch
    const int lane = t & 63;
    const int ch = lane & 31, h = lane >> 5;

    __shared__ float csm[8][32];
    __shared__ float zsm[8][32];
    float* cs = csm[b];
    float* zs = zsm[b];
    float* zbuf = ws + F_Z;

    if (h == 0) cs[ch] = ws[F_C0 + b * 32 + ch];
    __builtin_amdgcn_wave_barrier();

    const float4* blob = (const float4*)ws;  // layer l: float4 idx l*384+i*64+lane
    WBlob w0, w1, w2, w3;
    K2_PREFETCH(0, 0);
    K2_PREFETCH(1, 1);
    K2_PREFETCH(2, 2);
    K2_PREFETCH(3, 3);

    for (int l = 0; l < NL; l += 4) {
        K2_STEP(l + 0, 0);
        K2_STEP(l + 1, 1);
        K2_STEP(l + 2, 2);
        K2_STEP(l + 3, 3);
    }
}

// ------------------------------------------------------- K3a: skip matvec
__global__ __launch_bounds__(256) void k3a_skip(
    const float* __restrict__ skip_w, float* __restrict__ ws)
{
    const int l = blockIdx.x, b = blockIdx.y, t = threadIdx.x;
    __shared__ __align__(16) float zsm[32];
    if (t < 32) zsm[t] = ws[F_Z + (l * 8 + b) * 32 + t];
    __syncthreads();
    const float4* w4 = (const float4*)(skip_w + (size_t)(l * 256 + t) * 32);
    const float4* z4 = (const float4*)zsm;
    float acc = 0.f;
#pragma unroll
    for (int i = 0; i < 8; ++i) {
        float4 wv = w4[i], zv = z4[i];
        acc += wv.x*zv.x + wv.y*zv.y + wv.z*zv.z + wv.w*zv.w;
    }
    atomicAdd(&ws[F_H + b * 256 + t], acc);
}

// --------------------------------------------------- K3b: end1 + end2 + out
__global__ __launch_bounds__(256) void k3b_end(
    const float* __restrict__ end1_w, const float* __restrict__ end1_b,
    const float* __restrict__ end2_w, const float* __restrict__ end2_b,
    float* __restrict__ ws, float* __restrict__ out)
{
    const int q = blockIdx.x, b = blockIdx.y, t = threadIdx.x;
    __shared__ __align__(16) float hsm[256];
    __shared__ float psum[64][5];
    const int p = t >> 6, oc = t & 63, row = q * 64 + oc;

    float4 wreg[16];                     // start weight loads first
    const float4* wp = (const float4*)(end1_w + (size_t)row * 256 + p * 64);
#pragma unroll
    for (int i = 0; i < 16; ++i) wreg[i] = wp[i];

    hsm[t] = fmaxf(ws[F_H + b * 256 + t], 0.f);   // relu(skip_sum)
    __syncthreads();
    const float4* h4 = (const float4*)(hsm + p * 64);
    float acc = 0.f;
#pragma unroll
    for (int i = 0; i < 16; ++i) {
        float4 wv = wreg[i], hv = h4[i];
        acc += wv.x*hv.x + wv.y*hv.y + wv.z*hv.z + wv.w*hv.w;
    }
    psum[oc][p] = acc;
    __syncthreads();
    if (t < 64) {
        const int rr = q * 64 + t;
        float e = psum[t][0] + psum[t][1] + psum[t][2] + psum[t][3]
                + end1_b[rr];
        e = fmaxf(e, 0.f);
        float pe = e * end2_w[rr];
#pragma unroll
        for (int off = 32; off > 0; off >>= 1)
            pe += __shfl_down(pe, off, 64);
        if (t == 0) {
            float* obuf = ws + F_OB;
            int* cnt = (int*)(ws + F_CNT);
            atomicAdd(&obuf[b], pe);
            __threadfence();
            int old = __hip_atomic_fetch_add(&cnt[b], 1, __ATOMIC_ACQ_REL,
                                             __HIP_MEMORY_SCOPE_AGENT);
            if (old == 3) {   // last of the 4 quarter-blocks for this batch
                float tot = __hip_atomic_load(&obuf[b], __ATOMIC_ACQUIRE,
                                              __HIP_MEMORY_SCOPE_AGENT);
                out[b] = tot + end2_b[0];
            }
        }
    }
}

extern "C" void kernel_launch(void* const* d_in, const int* in_sizes, int n_in,
                              void* d_out, int out_size, void* d_ws, size_t ws_size,
                              hipStream_t stream) {
    const float* x        = (const float*)d_in[0];
    const float* start_w  = (const float*)d_in[1];
    const float* filter_w = (const float*)d_in[2];
    const float* gate_w   = (const float*)d_in[3];
    const float* res_w    = (const float*)d_in[4];
    const float* skip_w   = (const float*)d_in[5];
    const float* end1_w   = (const float*)d_in[6];
    const float* end1_b   = (const float*)d_in[7];
    const float* end2_w   = (const float*)d_in[8];
    const float* end2_b   = (const float*)d_in[9];
    float* out = (float*)d_out;
    float* ws  = (float*)d_ws;

    k1_prep <<<241, 256, 0, stream>>>(x, start_w, filter_w, gate_w, res_w, ws);
    k2_recur<<<1, 512, 0, stream>>>(ws);
    k3a_skip<<<dim3(NL, 8), 256, 0, stream>>>(skip_w, ws);
    k3b_end <<<dim3(4, 8), 256, 0, stream>>>(end1_w, end1_b, end2_w, end2_b,
                                             ws, out);
}